// Round 1
// baseline (91.919 us; speedup 1.0000x reference)
//
#include <hip/hip_runtime.h>
#include <cstdint>

#define BATCH   16384
#define INDIM   512
#define OUTDIM  128
#define NINT    31
#define NALL    63
#define BM      64
#define KCHUNK  128
#define NCHUNKS (INDIM / KCHUNK)
#define THREADS 256

typedef __attribute__((ext_vector_type(8))) short s8v;   // 8 bf16 in 4 VGPRs
typedef __attribute__((ext_vector_type(4))) float f4v;   // MFMA acc

__device__ __forceinline__ unsigned short f2bf(float f) {
    unsigned int u = __builtin_bit_cast(unsigned int, f);
    u = (u + 0x7FFFu + ((u >> 16) & 1u)) >> 16;   // RNE
    return (unsigned short)u;
}

// XOR swizzle: spreads 16B fragment slots across bank quads; bits 3-5 of elem idx
#define SWZ(r, k) ((k) ^ (((r) & 7) << 3))

__global__ __launch_bounds__(THREADS) void mixnode_kernel(
    const float* __restrict__ x, const float* __restrict__ W,
    const float* __restrict__ bvec, const float* __restrict__ gamma,
    const float* __restrict__ leaf, float* __restrict__ out)
{
    // Region A (32KB) is time-shared: [x|W] staging during P1/P2, [leafT|cbf] during P3/P4.
    __shared__ __align__(16) unsigned char regionA[32768];
    __shared__ __align__(16) float Lg[BM][68];   // logits, padded stride (bank spread)
    __shared__ float gsm0[NINT], gsm1[NINT];
    __shared__ float bsh[64];

    unsigned short (*xbf)[KCHUNK] = (unsigned short(*)[KCHUNK])regionA;            // [64][128] bf16
    unsigned short (*wbf)[KCHUNK] = (unsigned short(*)[KCHUNK])(regionA + 16384);  // [64][128] bf16
    unsigned short (*leafT)[64]   = (unsigned short(*)[64])regionA;                // [128 col][64 node]
    unsigned short (*cbf)[64]     = (unsigned short(*)[64])(regionA + 16384);      // [64 row][64 node]

    const int t    = threadIdx.x;
    const int lane = t & 63;
    const int wv   = t >> 6;        // wave id 0..3
    const int g    = lane >> 4;     // lane group 0..3
    const int lm   = lane & 15;
    const int row0 = blockIdx.x * BM;

    // batch-independent: softmax(gamma) and bias into LDS
    if (t < NINT) {
        float g0 = gamma[2*t], g1 = gamma[2*t+1];
        float m  = fmaxf(g0, g1);
        float e0 = __expf(g0 - m), e1 = __expf(g1 - m);
        float inv = 1.0f / (e0 + e1);
        gsm0[t] = e0 * inv; gsm1[t] = e1 * inv;
    }
    if (t < 64) bsh[t] = (t < 62) ? bvec[t] : 0.0f;

    // ---------------- P1+P2: logits = x @ W^T via bf16 MFMA, K-chunked ----------------
    f4v acc[4] = {};
    for (int ch = 0; ch < NCHUNKS; ++ch) {
        const int kc = ch * KCHUNK;
        __syncthreads();   // previous chunk's MFMA reads done before overwrite
        #pragma unroll
        for (int i = 0; i < 8; ++i) {       // 2048 float4 / 256 threads
            int f  = i * THREADS + t;
            int r  = f >> 5;                // tile row 0..63
            int c4 = f & 31;
            int k0 = c4 * 4;
            int p  = SWZ(r, k0);            // XOR keeps 4-elem groups contiguous
            float4 xv = *(const float4*)(x + (size_t)(row0 + r) * INDIM + kc + k0);
            *(ushort4*)&xbf[r][p] = make_ushort4(f2bf(xv.x), f2bf(xv.y), f2bf(xv.z), f2bf(xv.w));
            float4 wvv = make_float4(0.f, 0.f, 0.f, 0.f);
            if (r < 62) wvv = *(const float4*)(W + (size_t)r * INDIM + kc + k0);  // rows 62,63 zero
            *(ushort4*)&wbf[r][p] = make_ushort4(f2bf(wvv.x), f2bf(wvv.y), f2bf(wvv.z), f2bf(wvv.w));
        }
        __syncthreads();
        #pragma unroll
        for (int ks = 0; ks < KCHUNK / 32; ++ks) {
            int k0 = ks * 32 + 8 * g;       // lane's 8-elem k-slot (same bijection both operands)
            s8v a = *(const s8v*)&xbf[16*wv + lm][SWZ(lm, k0)];
            #pragma unroll
            for (int c = 0; c < 4; ++c) {
                s8v b = *(const s8v*)&wbf[16*c + lm][SWZ(lm, k0)];
                acc[c] = __builtin_amdgcn_mfma_f32_16x16x32_bf16(a, b, acc[c], 0, 0, 0);
            }
        }
    }
    // C/D layout (HW-verified): col = lane&15, row = 4*(lane>>4) + reg
    #pragma unroll
    for (int c = 0; c < 4; ++c)
        #pragma unroll
        for (int r = 0; r < 4; ++r)
            Lg[16*wv + 4*g + r][16*c + lm] = acc[c][r];
    __syncthreads();

    // ---------------- P3: per-row tree walk (wave0) || leaf^T bf16 staging (waves 1-3) ----
    if (t < BM) {
        const int row = t;
        float Pp[NALL];
        float cval[64];
        Pp[0] = 1.0f;
        #pragma unroll
        for (int n = 0; n < NINT; ++n) {    // fully unrolled: all indices compile-time
            float l0 = Lg[row][2*n]   + bsh[2*n];
            float l1 = Lg[row][2*n+1] + bsh[2*n+1];
            float r1 = 1.0f / (1.0f + __expf(l0 - l1));  // softmax pair, overflow-safe
            float base = Pp[n] * gsm0[n];
            Pp[2*n+1] = base * (1.0f - r1);
            Pp[2*n+2] = base * r1;
            cval[n] = Pp[n] * gsm1[n];      // internal node's leaf coefficient
        }
        #pragma unroll
        for (int n = NINT; n < NALL; ++n) cval[n] = Pp[n];  // pure leaves
        cval[63] = 0.0f;                     // pad node
        #pragma unroll
        for (int c2 = 0; c2 < 8; ++c2) {     // pack 8 bf16 -> one 16B swizzled write
            int p = SWZ(row, 8*c2);
            unsigned int a0 = (unsigned)f2bf(cval[8*c2+0]) | ((unsigned)f2bf(cval[8*c2+1]) << 16);
            unsigned int a1 = (unsigned)f2bf(cval[8*c2+2]) | ((unsigned)f2bf(cval[8*c2+3]) << 16);
            unsigned int a2 = (unsigned)f2bf(cval[8*c2+4]) | ((unsigned)f2bf(cval[8*c2+5]) << 16);
            unsigned int a3 = (unsigned)f2bf(cval[8*c2+6]) | ((unsigned)f2bf(cval[8*c2+7]) << 16);
            *(uint4*)&cbf[row][p] = make_uint4(a0, a1, a2, a3);
        }
    } else {
        for (int f = t - 64; f < NALL * 32; f += 192) {   // 63 nodes * 32 float4
            int n  = f >> 5;
            int c4 = f & 31;
            float4 lv = *(const float4*)(leaf + (size_t)n * OUTDIM + c4 * 4);
            int col = c4 * 4;
            leafT[col+0][SWZ(col+0, n)] = f2bf(lv.x);
            leafT[col+1][SWZ(col+1, n)] = f2bf(lv.y);
            leafT[col+2][SWZ(col+2, n)] = f2bf(lv.z);
            leafT[col+3][SWZ(col+3, n)] = f2bf(lv.w);
        }
        int col = t - 64;
        if (col < OUTDIM) leafT[col][SWZ(col, 63)] = 0;   // pad node: avoid NaN*0
    }
    __syncthreads();

    // ---------------- P4: Out[64][128] = C @ leaf via bf16 MFMA (K=64) ----------------
    f4v o[8] = {};
    #pragma unroll
    for (int kw = 0; kw < 2; ++kw) {
        int k0 = kw * 32 + 8 * g;
        s8v a = *(const s8v*)&cbf[16*wv + lm][SWZ(lm, k0)];
        #pragma unroll
        for (int nt = 0; nt < 8; ++nt) {
            s8v b = *(const s8v*)&leafT[16*nt + lm][SWZ(lm, k0)];
            o[nt] = __builtin_amdgcn_mfma_f32_16x16x32_bf16(a, b, o[nt], 0, 0, 0);
        }
    }
    #pragma unroll
    for (int nt = 0; nt < 8; ++nt)
        #pragma unroll
        for (int r = 0; r < 4; ++r)
            out[(size_t)(row0 + 16*wv + 4*g + r) * OUTDIM + 16*nt + lm] = o[nt][r];
}

extern "C" void kernel_launch(void* const* d_in, const int* in_sizes, int n_in,
                              void* d_out, int out_size, void* d_ws, size_t ws_size,
                              hipStream_t stream) {
    const float* x     = (const float*)d_in[0];
    const float* W     = (const float*)d_in[1];
    const float* b     = (const float*)d_in[2];
    const float* gamma = (const float*)d_in[3];
    const float* leaf  = (const float*)d_in[4];
    float* out = (float*)d_out;
    hipLaunchKernelGGL(mixnode_kernel, dim3(BATCH / BM), dim3(THREADS), 0, stream,
                       x, W, b, gamma, leaf, out);
}